// Round 15
// baseline (184.693 us; speedup 1.0000x reference)
//
#include <hip/hip_runtime.h>
#include <math.h>

#define N_NODES 50000
#define N_EDGES 800000
#define NBUCKET 196   // ceil(50000/256), bucket = dst>>8
#define CHUNK 4096
#define NCHUNK 196    // ceil(800000/4096)
#define SCAN_N (NBUCKET * NCHUNK)  // 38416
#define SB_A 151      // ceil(SCAN_N/256)
#define SB_B 196      // ceil(N_NODES/256)
#define NSB (SB_A + SB_B)          // 347
#define EPT 16        // edges per thread in scatter_coarse
#define CAP_FINE 8192
#define MAXEPAD (N_EDGES + N_NODES * 4)
#define XELEMS (N_NODES * 13)      // 650000
#define XCONV_B 32

typedef __attribute__((ext_vector_type(8))) _Float16 f16x8;
typedef __attribute__((ext_vector_type(4))) float f32x4;

__device__ __forceinline__ int roundup4(int v) { return (v + 3) & ~3; }

__device__ __forceinline__ float upw(int e) {  // unpack fp16 weight from bits 31:16
    unsigned short u = (unsigned short)(((unsigned)e) >> 16);
    return (float)__builtin_bit_cast(_Float16, u);
}

// ---------------- block-wide exclusive scan helper ----------------

__device__ __forceinline__ int block_excl_scan(int v, int* wsum) {
    int t = threadIdx.x, lane = t & 63, w = t >> 6;
    int sc = v;
    #pragma unroll
    for (int o = 1; o < 64; o <<= 1) {
        int u = __shfl_up(sc, o, 64);
        if (lane >= o) sc += u;
    }
    if (lane == 63) wsum[w] = sc;
    __syncthreads();
    int add = 0;
    #pragma unroll
    for (int j = 0; j < 4; ++j) if (j < w) add += wsum[j];
    return add + sc - v;  // exclusive
}

// ---- pass 1: per-chunk coarse histogram + per-dst counts (+ fused wconv + x->fp16) ----

__global__ void hist_kernel(const int* __restrict__ dst, int* __restrict__ h,
                            int* __restrict__ counts,
                            const float* __restrict__ W1r, const float* __restrict__ W1o,
                            const float* __restrict__ W2r, const float* __restrict__ W2o,
                            const float* __restrict__ W3r, const float* __restrict__ W3o,
                            _Float16* __restrict__ wfrag,
                            const float* __restrict__ x, _Float16* __restrict__ xh) {
    if (blockIdx.x >= NCHUNK + 3) {
        int b = blockIdx.x - (NCHUNK + 3);
        for (int i = b * 256 + threadIdx.x; i < XELEMS; i += XCONV_B * 256)
            xh[i] = (_Float16)x[i];
        return;
    }
    if (blockIdx.x >= NCHUNK) {
        int b = blockIdx.x - NCHUNK, t = threadIdx.x;
        const float* Wr = (b == 0) ? W1r : (b == 1) ? W2r : W3r;
        const float* Wo = (b == 0) ? W1o : (b == 1) ? W2o : W3o;
        _Float16* out = wfrag + (size_t)b * 8192;
        for (int i = t; i < 1024; i += 256) {
            int frag = i >> 6, lane = i & 63;
            int m = frag >> 3, ct = (frag >> 1) & 3, ks = frag & 1;
            int col = ct * 16 + (lane & 15);
            int kb = ks * 32 + (lane >> 4) * 8;
            const float* W = m ? Wo : Wr;
            f16x8 v;
            #pragma unroll
            for (int j = 0; j < 8; ++j) v[j] = (_Float16)W[(kb + j) * 64 + col];
            *(f16x8*)&out[(size_t)i * 8] = v;
        }
        return;
    }
    __shared__ int hist[NBUCKET];
    for (int i = threadIdx.x; i < NBUCKET; i += 256) hist[i] = 0;
    __syncthreads();
    int base = blockIdx.x * CHUNK;
    int n = min(CHUNK, N_EDGES - base);
    for (int k = threadIdx.x; k < n; k += 256) {
        int d = dst[base + k];
        atomicAdd(&hist[d >> 8], 1);
        atomicAdd(&counts[d], 1);
    }
    __syncthreads();
    for (int i = threadIdx.x; i < NBUCKET; i += 256)
        h[i * NCHUNK + blockIdx.x] = hist[i];
}

// ---------------- single-dispatch dual-region scan (decoupled aggregates) ----------------
// All NSB=347 blocks are co-resident (each tiny), so each block publishes its aggregate
// with a device-scope atomic and sums predecessors' aggregates. Exact & deterministic.

__global__ void scan_fused(int* __restrict__ h, int* __restrict__ offs,
                           const int* __restrict__ counts, int* __restrict__ status) {
    __shared__ int wsum[4];
    __shared__ int blkagg, sbase;
    int bid = blockIdx.x, t = threadIdx.x;
    int v;
    if (bid < SB_A) {
        int i = bid * 256 + t;
        v = (i < SCAN_N) ? h[i] : 0;
    } else {
        int j = (bid - SB_A) * 256 + t;
        v = (j < N_NODES) ? roundup4(counts[j]) : 0;
    }
    int e = block_excl_scan(v, wsum);
    if (t == 255) blkagg = e + v;
    __syncthreads();
    if (t == 0)
        __hip_atomic_store(&status[bid], (blkagg << 1) | 1, __ATOMIC_RELEASE,
                           __HIP_MEMORY_SCOPE_AGENT);
    int lo = (bid < SB_A) ? 0 : SB_A;
    if (t < 64) {
        int acc = 0;
        for (int p = lo + t; p < bid; p += 64) {
            int s;
            do {
                s = __hip_atomic_load(&status[p], __ATOMIC_ACQUIRE, __HIP_MEMORY_SCOPE_AGENT);
            } while (!(s & 1));
            acc += s >> 1;
        }
        #pragma unroll
        for (int o = 1; o < 64; o <<= 1) acc += __shfl_xor(acc, o, 64);
        if (t == 0) sbase = acc;
    }
    __syncthreads();
    int base = sbase;
    if (bid < SB_A) {
        int i = bid * 256 + t;
        if (i < SCAN_N) h[i] = e + base;
    } else {
        int j = (bid - SB_A) * 256 + t;
        if (j < N_NODES) {
            offs[j] = e + base;
            if (j == N_NODES - 1) offs[N_NODES] = e + base + v;
        }
    }
}

// ---------------- pass 2: register-staged LDS bucket sort, coalesced flush ----------------

__launch_bounds__(256, 4)
__global__ void scatter_coarse(const int* __restrict__ src, const int* __restrict__ dst,
                               const float* __restrict__ ew, const int* __restrict__ hs,
                               int2* __restrict__ ecoarse) {
    __shared__ int cnt[NBUCKET];
    __shared__ int excl[NBUCKET];
    __shared__ int cur[NBUCKET];
    __shared__ int gbase[NBUCKET];
    __shared__ int wsum[4];
    __shared__ int2 stage[CHUNK];

    int t = threadIdx.x;
    int base = blockIdx.x * CHUNK;
    int n = min(CHUNK, N_EDGES - base);

    for (int i = t; i < NBUCKET; i += 256) {
        cnt[i] = 0;
        gbase[i] = hs[i * NCHUNK + blockIdx.x];
    }
    __syncthreads();

    int rx[EPT];
    float rw[EPT];
    #pragma unroll
    for (int j = 0; j < EPT; ++j) {
        int k = t + j * 256;
        if (k < n) {
            int e = base + k;
            int d = dst[e];
            rx[j] = (d << 16) | src[e];
            rw[j] = ew[e];
            atomicAdd(&cnt[d >> 8], 1);
        }
    }
    __syncthreads();

    {
        int v = (t < NBUCKET) ? cnt[t] : 0;
        int e = block_excl_scan(v, wsum);
        if (t < NBUCKET) { excl[t] = e; cur[t] = e; }
    }
    __syncthreads();

    #pragma unroll
    for (int j = 0; j < EPT; ++j) {
        int k = t + j * 256;
        if (k < n) {
            int b = ((unsigned)rx[j]) >> 24;
            int p = atomicAdd(&cur[b], 1);
            stage[p] = make_int2(rx[j], __float_as_int(rw[j]));
        }
    }
    __syncthreads();

    for (int k = t; k < n; k += 256) {
        int2 r = stage[k];
        int b = ((unsigned)r.x) >> 24;
        ecoarse[gbase[b] + (k - excl[b])] = r;
    }
}

// ---- pass 3: per-bucket fine sort into PADDED CSR of 4-byte packed records ----
// packed = src(15:0) | fp16(ew)(31:16). pad slots = 0 (src 0, weight +0.0).

__launch_bounds__(256)
__global__ void fine_sort(const int* __restrict__ h, const int* __restrict__ offs,
                          const int2* __restrict__ ecoarse, int* __restrict__ epack) {
    int b = blockIdx.x, t = threadIdx.x;
    __shared__ int cur[256];
    __shared__ int stage[CAP_FINE];
    int bstartU = h[b * NCHUNK];
    int bendU = (b == NBUCKET - 1) ? N_EDGES : h[(b + 1) * NCHUNK];
    int nbU = bendU - bstartU;
    int P = offs[b << 8];
    int nodeEnd = min((b + 1) << 8, N_NODES);
    int plen = offs[nodeEnd] - P;
    int dstv = (b << 8) + t;
    cur[t] = (dstv < N_NODES) ? offs[dstv] - P : 0;
    __syncthreads();
    if (plen <= CAP_FINE) {
        for (int k = t; k < plen; k += 256) stage[k] = 0;
        __syncthreads();
        for (int k = t; k < nbU; k += 256) {
            int2 r = ecoarse[bstartU + k];
            int d = (((unsigned)r.x) >> 16) & 255;
            unsigned short hw = __builtin_bit_cast(unsigned short, (_Float16)__int_as_float(r.y));
            int p = atomicAdd(&cur[d], 1);
            stage[p] = (r.x & 0xFFFF) | ((int)hw << 16);
        }
        __syncthreads();
        for (int k = t; k < plen; k += 256) epack[P + k] = stage[k];
    } else {  // fallback, never expected
        for (int k = t; k < plen; k += 256) epack[P + k] = 0;
        __syncthreads();
        for (int k = t; k < nbU; k += 256) {
            int2 r = ecoarse[bstartU + k];
            int d = (((unsigned)r.x) >> 16) & 255;
            unsigned short hw = __builtin_bit_cast(unsigned short, (_Float16)__int_as_float(r.y));
            int p = atomicAdd(&cur[d], 1);
            epack[P + p] = (r.x & 0xFFFF) | ((int)hw << 16);
        }
    }
}

// ---------------- bcast via readlane (VALU pipe) ----------------

__device__ __forceinline__ float bcast(float v, int k) {
    return __int_as_float(__builtin_amdgcn_readlane(__float_as_int(v), k));
}

// ---------------- layer 0 fused: gather(13, fp16 x) + dual-GEMM + bias + relu -> fp16 ----

__launch_bounds__(256)
__global__ void layer0_fused(const int* __restrict__ offs, const int* __restrict__ epack,
                             const _Float16* __restrict__ xh, const float* __restrict__ Wrel,
                             const float* __restrict__ bias, const float* __restrict__ Wroot,
                             _Float16* __restrict__ h0) {
    int wid = (blockIdx.x * blockDim.x + threadIdx.x) >> 6;
    int lane = threadIdx.x & 63;
    float wr[13], wo[13];
    #pragma unroll
    for (int k = 0; k < 13; ++k) {
        wr[k] = Wrel[k * 64 + lane];
        wo[k] = Wroot[k * 64 + lane];
    }
    float bc = bias[lane];
    int q = lane >> 4, f = lane & 15;
    int beg = offs[wid], end = offs[wid + 1];
    float acc = 0.f;
    bool fv = (f < 13);
    int i = beg + q;
    for (; i + 4 < end; i += 8) {
        int e0 = epack[i], e1 = epack[i + 4];
        float v0 = fv ? (float)xh[(size_t)(e0 & 0xFFFF) * 13 + f] : 0.f;
        float v1 = fv ? (float)xh[(size_t)(e1 & 0xFFFF) * 13 + f] : 0.f;
        acc = fmaf(upw(e0), v0, acc);
        acc = fmaf(upw(e1), v1, acc);
    }
    if (i < end) {
        int e = epack[i];
        float v = fv ? (float)xh[(size_t)(e & 0xFFFF) * 13 + f] : 0.f;
        acc = fmaf(upw(e), v, acc);
    }
    acc += __shfl_xor(acc, 16, 64);
    acc += __shfl_xor(acc, 32, 64);
    float hv = (lane < 13) ? (float)xh[(size_t)wid * 13 + lane] : 0.f;
    float a0 = bc, a1 = 0.f, a2 = 0.f, a3 = 0.f;
    #pragma unroll
    for (int k = 0; k + 2 <= 13; k += 2) {
        a0 = fmaf(bcast(acc, k), wr[k], a0);
        a1 = fmaf(bcast(hv, k), wo[k], a1);
        a2 = fmaf(bcast(acc, k + 1), wr[k + 1], a2);
        a3 = fmaf(bcast(hv, k + 1), wo[k + 1], a3);
    }
    a0 = fmaf(bcast(acc, 12), wr[12], a0);
    a1 = fmaf(bcast(hv, 12), wo[12], a1);
    float o = fmaxf((a0 + a2) + (a1 + a3), 0.f);
    h0[(size_t)wid * 64 + lane] = (_Float16)o;
}

// ---------------- fused layer (round-9 gather, 4B packed records) ----------------

template <bool FINAL>
__launch_bounds__(256)
__global__ void layer_fused(const int* __restrict__ offs, const int* __restrict__ epack,
                            const _Float16* __restrict__ hin, const _Float16* __restrict__ wfrag_l,
                            const float* __restrict__ bias, _Float16* __restrict__ hout,
                            const float* __restrict__ Wrel4, const float* __restrict__ Wroot4,
                            float* __restrict__ z, float* __restrict__ root) {
    __shared__ __align__(16) _Float16 aggrHi[32][72];
    __shared__ __align__(16) _Float16 aggrLo[32][72];
    __shared__ float zpart[4][32], rpart[4][32];
    int t = threadIdx.x;
    int rowbase = blockIdx.x * 32;
    int w = t >> 6, lane = t & 63;

    // issue B-fragment + bias loads early (overlap with gather)
    f16x8 br0 = *(const f16x8*)&wfrag_l[(size_t)(((0 * 4 + w) * 2 + 0) * 64 + lane) * 8];
    f16x8 br1 = *(const f16x8*)&wfrag_l[(size_t)(((0 * 4 + w) * 2 + 1) * 64 + lane) * 8];
    f16x8 bo0 = *(const f16x8*)&wfrag_l[(size_t)(((1 * 4 + w) * 2 + 0) * 64 + lane) * 8];
    f16x8 bo1 = *(const f16x8*)&wfrag_l[(size_t)(((1 * 4 + w) * 2 + 1) * 64 + lane) * 8];
    int r = lane & 15, kq = lane >> 4;
    float bc = bias[w * 16 + r];
    float w4rv = 0.f, w4ov = 0.f;
    if (FINAL) { w4rv = Wrel4[w * 16 + r]; w4ov = Wroot4[w * 16 + r]; }

    // ---- gather phase (round-9 form, packed records: 4 edges per int4) ----
    int qw = t >> 4, l = t & 15;
    int hi8 = l >> 3, f8 = l & 7;
    #pragma unroll
    for (int rr = 0; rr < 2; ++rr) {
        int node = rowbase + qw + rr * 16;
        float a[8] = {0.f, 0.f, 0.f, 0.f, 0.f, 0.f, 0.f, 0.f};
        if (node < N_NODES) {
            int beg = offs[node], end = offs[node + 1];
            int i = beg;
            for (; i + 4 < end; i += 8) {
                int4 pk0 = *(const int4*)(epack + i);
                int4 pk1 = *(const int4*)(epack + i + 4);
                int e0 = hi8 ? pk0.z : pk0.x;
                int e1 = hi8 ? pk0.w : pk0.y;
                int e2 = hi8 ? pk1.z : pk1.x;
                int e3 = hi8 ? pk1.w : pk1.y;
                f16x8 r0 = *(const f16x8*)(hin + (size_t)(e0 & 0xFFFF) * 64 + f8 * 8);
                f16x8 r1 = *(const f16x8*)(hin + (size_t)(e1 & 0xFFFF) * 64 + f8 * 8);
                f16x8 r2 = *(const f16x8*)(hin + (size_t)(e2 & 0xFFFF) * 64 + f8 * 8);
                f16x8 r3 = *(const f16x8*)(hin + (size_t)(e3 & 0xFFFF) * 64 + f8 * 8);
                float w0 = upw(e0), w1 = upw(e1), w2 = upw(e2), w3 = upw(e3);
                #pragma unroll
                for (int j = 0; j < 8; ++j) {
                    a[j] = fmaf(w0, (float)r0[j], a[j]);
                    a[j] = fmaf(w1, (float)r1[j], a[j]);
                    a[j] = fmaf(w2, (float)r2[j], a[j]);
                    a[j] = fmaf(w3, (float)r3[j], a[j]);
                }
            }
            if (i < end) {   // exactly 4 remaining (rows padded to x4)
                int4 pk = *(const int4*)(epack + i);
                int e0 = hi8 ? pk.z : pk.x;
                int e1 = hi8 ? pk.w : pk.y;
                f16x8 r0 = *(const f16x8*)(hin + (size_t)(e0 & 0xFFFF) * 64 + f8 * 8);
                f16x8 r1 = *(const f16x8*)(hin + (size_t)(e1 & 0xFFFF) * 64 + f8 * 8);
                float w0 = upw(e0), w1 = upw(e1);
                #pragma unroll
                for (int j = 0; j < 8; ++j) {
                    a[j] = fmaf(w0, (float)r0[j], a[j]);
                    a[j] = fmaf(w1, (float)r1[j], a[j]);
                }
            }
        }
        #pragma unroll
        for (int j = 0; j < 8; ++j) a[j] += __shfl_xor(a[j], 8, 64);
        f16x8 wv;
        #pragma unroll
        for (int j = 0; j < 8; ++j) {
            _Float16 hh = (_Float16)a[j];
            wv[j] = hi8 ? (_Float16)(a[j] - (float)hh) : hh;
        }
        int row = qw + rr * 16;
        _Float16* dstp = hi8 ? &aggrLo[row][f8 * 8] : &aggrHi[row][f8 * 8];
        *(f16x8*)dstp = wv;
    }
    __syncthreads();

    // ---- MFMA phase: wave w owns column tile ct=w ----
    #pragma unroll
    for (int g = 0; g < 2; ++g) {
        int lr = g * 16 + r;
        int grow = min(rowbase + lr, N_NODES - 1);
        f32x4 acc = {bc, bc, bc, bc};
        {
            f16x8 Ah = *(const f16x8*)&aggrHi[lr][0 * 32 + kq * 8];
            f16x8 Al = *(const f16x8*)&aggrLo[lr][0 * 32 + kq * 8];
            f16x8 Ar = *(const f16x8*)&hin[(size_t)grow * 64 + 0 * 32 + kq * 8];
            acc = __builtin_amdgcn_mfma_f32_16x16x32_f16(Ah, br0, acc, 0, 0, 0);
            acc = __builtin_amdgcn_mfma_f32_16x16x32_f16(Al, br0, acc, 0, 0, 0);
            acc = __builtin_amdgcn_mfma_f32_16x16x32_f16(Ar, bo0, acc, 0, 0, 0);
        }
        {
            f16x8 Ah = *(const f16x8*)&aggrHi[lr][1 * 32 + kq * 8];
            f16x8 Al = *(const f16x8*)&aggrLo[lr][1 * 32 + kq * 8];
            f16x8 Ar = *(const f16x8*)&hin[(size_t)grow * 64 + 1 * 32 + kq * 8];
            acc = __builtin_amdgcn_mfma_f32_16x16x32_f16(Ah, br1, acc, 0, 0, 0);
            acc = __builtin_amdgcn_mfma_f32_16x16x32_f16(Al, br1, acc, 0, 0, 0);
            acc = __builtin_amdgcn_mfma_f32_16x16x32_f16(Ar, bo1, acc, 0, 0, 0);
        }
        if (FINAL) {
            #pragma unroll
            for (int j = 0; j < 4; ++j) {
                float o = fmaxf(acc[j], 0.f);
                float zz = o * w4rv, rv = o * w4ov;
                #pragma unroll
                for (int m = 1; m < 16; m <<= 1) {
                    zz += __shfl_xor(zz, m, 64);
                    rv += __shfl_xor(rv, m, 64);
                }
                if (r == 0) {
                    int lrow = g * 16 + (lane >> 4) * 4 + j;
                    zpart[w][lrow] = zz;
                    rpart[w][lrow] = rv;
                }
            }
        } else {
            #pragma unroll
            for (int j = 0; j < 4; ++j) {
                int row = rowbase + g * 16 + (lane >> 4) * 4 + j;
                if (row < N_NODES)
                    hout[(size_t)row * 64 + w * 16 + r] = (_Float16)fmaxf(acc[j], 0.f);
            }
        }
    }
    if (FINAL) {
        __syncthreads();
        if (t < 32) {
            int row = rowbase + t;
            if (row < N_NODES) {
                z[row] = zpart[0][t] + zpart[1][t] + zpart[2][t] + zpart[3][t];
                root[row] = rpart[0][t] + rpart[1][t] + rpart[2][t] + rpart[3][t];
            }
        }
    }
}

// ---------------- final scalar aggregation + sigmoid (4 lanes per node) ----------------

__launch_bounds__(256)
__global__ void final_aggr(const int* __restrict__ offs, const int* __restrict__ epack,
                           const float* __restrict__ z, const float* __restrict__ root,
                           const float* __restrict__ b4, float* __restrict__ out) {
    int tid = blockIdx.x * blockDim.x + threadIdx.x;
    int node = tid >> 2, g = tid & 3;
    if (node >= N_NODES) return;
    int beg = offs[node], end = offs[node + 1];
    float a = 0.f;
    int i = beg + g;
    for (; i + 4 < end; i += 8) {
        int e0 = epack[i], e1 = epack[i + 4];
        a = fmaf(upw(e0), z[e0 & 0xFFFF], a);
        a = fmaf(upw(e1), z[e1 & 0xFFFF], a);
    }
    if (i < end) {
        int e = epack[i];
        a = fmaf(upw(e), z[e & 0xFFFF], a);
    }
    a += __shfl_xor(a, 1, 64);
    a += __shfl_xor(a, 2, 64);
    if (g == 0) {
        float v = a + b4[0] + root[node];
        out[node] = 1.f / (1.f + expf(-v));
    }
}

// ---------------- launch ----------------

extern "C" void kernel_launch(void* const* d_in, const int* in_sizes, int n_in,
                              void* d_out, int out_size, void* d_ws, size_t ws_size,
                              hipStream_t stream) {
    const float* x = (const float*)d_in[0];
    const int* eidx = (const int*)d_in[1];
    const float* ew = (const float*)d_in[2];
    const float* Wrel[5];
    const float* brel[5];
    const float* Wroot[5];
    for (int i = 0; i < 5; ++i) {
        Wrel[i] = (const float*)d_in[3 + 3 * i];
        brel[i] = (const float*)d_in[4 + 3 * i];
        Wroot[i] = (const float*)d_in[5 + 3 * i];
    }
    const int* src = eidx;
    const int* dst = eidx + N_EDGES;
    float* out = (float*)d_out;

    char* ws = (char*)d_ws;
    size_t off = 0;
    auto alloc = [&](size_t bytes) -> void* {
        void* p = ws + off;
        off = (off + bytes + 255) & ~(size_t)255;
        return p;
    };
    int* h = (int*)alloc((size_t)(SCAN_N + 256) * 4);
    int* counts = (int*)alloc((size_t)(N_NODES + NSB + 64) * 4);  // counts + scan status
    int* status = counts + N_NODES;
    int* offs = (int*)alloc((size_t)(N_NODES + 1) * 4);
    int* epack = (int*)alloc((size_t)MAXEPAD * 4);
    _Float16* h0 = (_Float16*)alloc((size_t)N_NODES * 64 * 2);
    _Float16* h1 = (_Float16*)alloc((size_t)N_NODES * 64 * 2);
    _Float16* wfrag = (_Float16*)alloc((size_t)3 * 8192 * 2);
    _Float16* xh = (_Float16*)alloc((size_t)XELEMS * 2);
    float* z = (float*)alloc((size_t)N_NODES * 4);
    float* root = (float*)alloc((size_t)N_NODES * 4);
    int2* ecoarse = (int2*)h0;  // disjoint lifetime: sort phase only (6.4 MB == h0 size)
    (void)ws_size; (void)in_sizes; (void)n_in; (void)out_size;

    // ---- CSR build: counting sort, rows padded to x4 (+fused wconv + x->fp16) ----
    hipMemsetAsync(counts, 0, (size_t)(N_NODES + NSB + 64) * 4, stream);  // counts + status
    hist_kernel<<<NCHUNK + 3 + XCONV_B, 256, 0, stream>>>(dst, h, counts,
                                                Wrel[1], Wroot[1], Wrel[2], Wroot[2],
                                                Wrel[3], Wroot[3], wfrag, x, xh);
    scan_fused<<<NSB, 256, 0, stream>>>(h, offs, counts, status);
    scatter_coarse<<<NCHUNK, 256, 0, stream>>>(src, dst, ew, h, ecoarse);
    fine_sort<<<NBUCKET, 256, 0, stream>>>(h, offs, ecoarse, epack);

    const int NODE_BLOCKS = N_NODES * 64 / 256;  // 12500
    const int FB = (N_NODES + 31) / 32;          // 1563

    // ---- layer 0 (fused gather13 + VALU GEMM, fp16 x) -> h0 fp16 ----
    layer0_fused<<<NODE_BLOCKS, 256, 0, stream>>>(offs, epack, xh, Wrel[0], brel[0], Wroot[0], h0);

    // ---- layers 1..3 fused gather + MFMA ----
    layer_fused<false><<<FB, 256, 0, stream>>>(offs, epack, h0, wfrag, brel[1], h1,
                                               nullptr, nullptr, nullptr, nullptr);
    layer_fused<false><<<FB, 256, 0, stream>>>(offs, epack, h1, wfrag + 8192, brel[2], h0,
                                               nullptr, nullptr, nullptr, nullptr);
    layer_fused<true><<<FB, 256, 0, stream>>>(offs, epack, h0, wfrag + 16384, brel[3], nullptr,
                                              Wrel[4], Wroot[4], z, root);

    // ---- layer 4 scalar aggregation + sigmoid ----
    final_aggr<<<(N_NODES * 4 + 255) / 256, 256, 0, stream>>>(offs, epack, z, root, brel[4], out);
}

// Round 16
// 174.285 us; speedup vs baseline: 1.0597x; 1.0597x over previous
//
#include <hip/hip_runtime.h>
#include <math.h>

#define N_NODES 50000
#define N_EDGES 800000
#define NBUCKET 196   // ceil(50000/256), bucket = dst>>8
#define CHUNK 4096
#define NCHUNK 196    // ceil(800000/4096)
#define SCAN_N (NBUCKET * NCHUNK)  // 38416
#define SB_A 151      // ceil(SCAN_N/256)
#define SB_B 196      // ceil(N_NODES/256)
#define NSB (SB_A + SB_B)          // 347
#define EPT 16        // edges per thread in scatter_coarse
#define CAP_FINE 8192
#define MAXEPAD (N_EDGES + N_NODES * 4)
#define XELEMS (N_NODES * 13)      // 650000
#define XCONV_B 32

typedef __attribute__((ext_vector_type(8))) _Float16 f16x8;
typedef __attribute__((ext_vector_type(4))) float f32x4;

__device__ __forceinline__ int roundup4(int v) { return (v + 3) & ~3; }

__device__ __forceinline__ float upw(int e) {  // unpack fp16 weight from bits 31:16
    unsigned short u = (unsigned short)(((unsigned)e) >> 16);
    return (float)__builtin_bit_cast(_Float16, u);
}

// ---------------- block-wide exclusive scan helper ----------------

__device__ __forceinline__ int block_excl_scan(int v, int* wsum) {
    int t = threadIdx.x, lane = t & 63, w = t >> 6;
    int sc = v;
    #pragma unroll
    for (int o = 1; o < 64; o <<= 1) {
        int u = __shfl_up(sc, o, 64);
        if (lane >= o) sc += u;
    }
    if (lane == 63) wsum[w] = sc;
    __syncthreads();
    int add = 0;
    #pragma unroll
    for (int j = 0; j < 4; ++j) if (j < w) add += wsum[j];
    return add + sc - v;  // exclusive
}

// ---- pass 1: per-chunk coarse histogram + per-dst counts (+ fused wconv + x->fp16) ----

__global__ void hist_kernel(const int* __restrict__ dst, int* __restrict__ h,
                            int* __restrict__ counts,
                            const float* __restrict__ W1r, const float* __restrict__ W1o,
                            const float* __restrict__ W2r, const float* __restrict__ W2o,
                            const float* __restrict__ W3r, const float* __restrict__ W3o,
                            _Float16* __restrict__ wfrag,
                            const float* __restrict__ x, _Float16* __restrict__ xh) {
    if (blockIdx.x >= NCHUNK + 3) {
        int b = blockIdx.x - (NCHUNK + 3);
        for (int i = b * 256 + threadIdx.x; i < XELEMS; i += XCONV_B * 256)
            xh[i] = (_Float16)x[i];
        return;
    }
    if (blockIdx.x >= NCHUNK) {
        int b = blockIdx.x - NCHUNK, t = threadIdx.x;
        const float* Wr = (b == 0) ? W1r : (b == 1) ? W2r : W3r;
        const float* Wo = (b == 0) ? W1o : (b == 1) ? W2o : W3o;
        _Float16* out = wfrag + (size_t)b * 8192;
        for (int i = t; i < 1024; i += 256) {
            int frag = i >> 6, lane = i & 63;
            int m = frag >> 3, ct = (frag >> 1) & 3, ks = frag & 1;
            int col = ct * 16 + (lane & 15);
            int kb = ks * 32 + (lane >> 4) * 8;
            const float* W = m ? Wo : Wr;
            f16x8 v;
            #pragma unroll
            for (int j = 0; j < 8; ++j) v[j] = (_Float16)W[(kb + j) * 64 + col];
            *(f16x8*)&out[(size_t)i * 8] = v;
        }
        return;
    }
    __shared__ int hist[NBUCKET];
    for (int i = threadIdx.x; i < NBUCKET; i += 256) hist[i] = 0;
    __syncthreads();
    int base = blockIdx.x * CHUNK;
    int n = min(CHUNK, N_EDGES - base);
    for (int k = threadIdx.x; k < n; k += 256) {
        int d = dst[base + k];
        atomicAdd(&hist[d >> 8], 1);
        atomicAdd(&counts[d], 1);
    }
    __syncthreads();
    for (int i = threadIdx.x; i < NBUCKET; i += 256)
        h[i * NCHUNK + blockIdx.x] = hist[i];
}

// ---------------- 2-dispatch dual-region scan ----------------

__global__ void scan_sums(const int* __restrict__ h, const int* __restrict__ counts,
                          int* __restrict__ blocksums) {
    __shared__ int wsum[4];
    int bid = blockIdx.x, t = threadIdx.x;
    int v;
    if (bid < SB_A) {
        int i = bid * 256 + t;
        v = (i < SCAN_N) ? h[i] : 0;
    } else {
        int j = (bid - SB_A) * 256 + t;
        v = (j < N_NODES) ? roundup4(counts[j]) : 0;
    }
    int lane = t & 63, w = t >> 6;
    int s = v;
    #pragma unroll
    for (int o = 1; o < 64; o <<= 1) s += __shfl_xor(s, o, 64);
    if (lane == 0) wsum[w] = s;
    __syncthreads();
    if (t == 0) blocksums[bid] = wsum[0] + wsum[1] + wsum[2] + wsum[3];
}

__global__ void scan_apply(int* __restrict__ h, int* __restrict__ offs,
                           const int* __restrict__ counts,
                           const int* __restrict__ blocksums) {
    __shared__ int sblk[NSB + 1];
    __shared__ int wsum[4];
    int bid = blockIdx.x, t = threadIdx.x;
    if (t < 64) {
        int carry = 0;
        for (int c = 0; c < NSB; c += 64) {
            int i = c + t;
            int v = (i < NSB) ? blocksums[i] : 0;
            int sc = v;
            #pragma unroll
            for (int o = 1; o < 64; o <<= 1) {
                int u = __shfl_up(sc, o, 64);
                if (t >= o) sc += u;
            }
            if (i < NSB) sblk[i] = carry + sc - v;
            carry += __shfl(sc, 63, 64);
        }
        if (t == 0) sblk[NSB] = carry;
    }
    __syncthreads();
    int v;
    if (bid < SB_A) {
        int i = bid * 256 + t;
        v = (i < SCAN_N) ? h[i] : 0;
        int e = block_excl_scan(v, wsum);
        int base = sblk[bid];
        if (i < SCAN_N) h[i] = e + base;
    } else {
        int j = (bid - SB_A) * 256 + t;
        v = (j < N_NODES) ? roundup4(counts[j]) : 0;
        int e = block_excl_scan(v, wsum);
        int base = sblk[bid] - sblk[SB_A];
        if (j < N_NODES) {
            offs[j] = e + base;
            if (j == N_NODES - 1) offs[N_NODES] = e + base + v;
        }
    }
}

// ---------------- pass 2: register-staged LDS bucket sort, coalesced flush ----------------

__launch_bounds__(256, 4)
__global__ void scatter_coarse(const int* __restrict__ src, const int* __restrict__ dst,
                               const float* __restrict__ ew, const int* __restrict__ hs,
                               int2* __restrict__ ecoarse) {
    __shared__ int cnt[NBUCKET];
    __shared__ int excl[NBUCKET];
    __shared__ int cur[NBUCKET];
    __shared__ int gbase[NBUCKET];
    __shared__ int wsum[4];
    __shared__ int2 stage[CHUNK];

    int t = threadIdx.x;
    int base = blockIdx.x * CHUNK;
    int n = min(CHUNK, N_EDGES - base);

    for (int i = t; i < NBUCKET; i += 256) {
        cnt[i] = 0;
        gbase[i] = hs[i * NCHUNK + blockIdx.x];
    }
    __syncthreads();

    int rx[EPT];
    float rw[EPT];
    #pragma unroll
    for (int j = 0; j < EPT; ++j) {
        int k = t + j * 256;
        if (k < n) {
            int e = base + k;
            int d = dst[e];
            rx[j] = (d << 16) | src[e];
            rw[j] = ew[e];
            atomicAdd(&cnt[d >> 8], 1);
        }
    }
    __syncthreads();

    {
        int v = (t < NBUCKET) ? cnt[t] : 0;
        int e = block_excl_scan(v, wsum);
        if (t < NBUCKET) { excl[t] = e; cur[t] = e; }
    }
    __syncthreads();

    #pragma unroll
    for (int j = 0; j < EPT; ++j) {
        int k = t + j * 256;
        if (k < n) {
            int b = ((unsigned)rx[j]) >> 24;
            int p = atomicAdd(&cur[b], 1);
            stage[p] = make_int2(rx[j], __float_as_int(rw[j]));
        }
    }
    __syncthreads();

    for (int k = t; k < n; k += 256) {
        int2 r = stage[k];
        int b = ((unsigned)r.x) >> 24;
        ecoarse[gbase[b] + (k - excl[b])] = r;
    }
}

// ---- pass 3: per-bucket fine sort into PADDED CSR of 4-byte packed records ----
// packed = src(15:0) | fp16(ew)(31:16). pad slots = 0 (src 0, weight +0.0).

__launch_bounds__(256)
__global__ void fine_sort(const int* __restrict__ h, const int* __restrict__ offs,
                          const int2* __restrict__ ecoarse, int* __restrict__ epack) {
    int b = blockIdx.x, t = threadIdx.x;
    __shared__ int cur[256];
    __shared__ int stage[CAP_FINE];
    int bstartU = h[b * NCHUNK];
    int bendU = (b == NBUCKET - 1) ? N_EDGES : h[(b + 1) * NCHUNK];
    int nbU = bendU - bstartU;
    int P = offs[b << 8];
    int nodeEnd = min((b + 1) << 8, N_NODES);
    int plen = offs[nodeEnd] - P;
    int dstv = (b << 8) + t;
    cur[t] = (dstv < N_NODES) ? offs[dstv] - P : 0;
    __syncthreads();
    if (plen <= CAP_FINE) {
        for (int k = t; k < plen; k += 256) stage[k] = 0;
        __syncthreads();
        for (int k = t; k < nbU; k += 256) {
            int2 r = ecoarse[bstartU + k];
            int d = (((unsigned)r.x) >> 16) & 255;
            unsigned short hw = __builtin_bit_cast(unsigned short, (_Float16)__int_as_float(r.y));
            int p = atomicAdd(&cur[d], 1);
            stage[p] = (r.x & 0xFFFF) | ((int)hw << 16);
        }
        __syncthreads();
        for (int k = t; k < plen; k += 256) epack[P + k] = stage[k];
    } else {  // fallback, never expected
        for (int k = t; k < plen; k += 256) epack[P + k] = 0;
        __syncthreads();
        for (int k = t; k < nbU; k += 256) {
            int2 r = ecoarse[bstartU + k];
            int d = (((unsigned)r.x) >> 16) & 255;
            unsigned short hw = __builtin_bit_cast(unsigned short, (_Float16)__int_as_float(r.y));
            int p = atomicAdd(&cur[d], 1);
            epack[P + p] = (r.x & 0xFFFF) | ((int)hw << 16);
        }
    }
}

// ---------------- bcast via readlane (VALU pipe) ----------------

__device__ __forceinline__ float bcast(float v, int k) {
    return __int_as_float(__builtin_amdgcn_readlane(__float_as_int(v), k));
}

// ---------------- layer 0 fused: gather(13, fp16 x) + dual-GEMM + bias + relu -> fp16 ----

__launch_bounds__(256)
__global__ void layer0_fused(const int* __restrict__ offs, const int* __restrict__ epack,
                             const _Float16* __restrict__ xh, const float* __restrict__ Wrel,
                             const float* __restrict__ bias, const float* __restrict__ Wroot,
                             _Float16* __restrict__ h0) {
    int wid = (blockIdx.x * blockDim.x + threadIdx.x) >> 6;
    int lane = threadIdx.x & 63;
    float wr[13], wo[13];
    #pragma unroll
    for (int k = 0; k < 13; ++k) {
        wr[k] = Wrel[k * 64 + lane];
        wo[k] = Wroot[k * 64 + lane];
    }
    float bc = bias[lane];
    int q = lane >> 4, f = lane & 15;
    int beg = offs[wid], end = offs[wid + 1];
    float acc = 0.f;
    bool fv = (f < 13);
    int i = beg + q;
    for (; i + 4 < end; i += 8) {
        int e0 = epack[i], e1 = epack[i + 4];
        float v0 = fv ? (float)xh[(size_t)(e0 & 0xFFFF) * 13 + f] : 0.f;
        float v1 = fv ? (float)xh[(size_t)(e1 & 0xFFFF) * 13 + f] : 0.f;
        acc = fmaf(upw(e0), v0, acc);
        acc = fmaf(upw(e1), v1, acc);
    }
    if (i < end) {
        int e = epack[i];
        float v = fv ? (float)xh[(size_t)(e & 0xFFFF) * 13 + f] : 0.f;
        acc = fmaf(upw(e), v, acc);
    }
    acc += __shfl_xor(acc, 16, 64);
    acc += __shfl_xor(acc, 32, 64);
    float hv = (lane < 13) ? (float)xh[(size_t)wid * 13 + lane] : 0.f;
    float a0 = bc, a1 = 0.f, a2 = 0.f, a3 = 0.f;
    #pragma unroll
    for (int k = 0; k + 2 <= 13; k += 2) {
        a0 = fmaf(bcast(acc, k), wr[k], a0);
        a1 = fmaf(bcast(hv, k), wo[k], a1);
        a2 = fmaf(bcast(acc, k + 1), wr[k + 1], a2);
        a3 = fmaf(bcast(hv, k + 1), wo[k + 1], a3);
    }
    a0 = fmaf(bcast(acc, 12), wr[12], a0);
    a1 = fmaf(bcast(hv, 12), wo[12], a1);
    float o = fmaxf((a0 + a2) + (a1 + a3), 0.f);
    h0[(size_t)wid * 64 + lane] = (_Float16)o;
}

// ---------------- fused layer (round-9 gather, 4B packed records) ----------------

template <bool FINAL>
__launch_bounds__(256)
__global__ void layer_fused(const int* __restrict__ offs, const int* __restrict__ epack,
                            const _Float16* __restrict__ hin, const _Float16* __restrict__ wfrag_l,
                            const float* __restrict__ bias, _Float16* __restrict__ hout,
                            const float* __restrict__ Wrel4, const float* __restrict__ Wroot4,
                            float* __restrict__ z, float* __restrict__ root) {
    __shared__ __align__(16) _Float16 aggrHi[32][72];
    __shared__ __align__(16) _Float16 aggrLo[32][72];
    __shared__ float zpart[4][32], rpart[4][32];
    int t = threadIdx.x;
    int rowbase = blockIdx.x * 32;
    int w = t >> 6, lane = t & 63;

    // issue B-fragment + bias loads early (overlap with gather)
    f16x8 br0 = *(const f16x8*)&wfrag_l[(size_t)(((0 * 4 + w) * 2 + 0) * 64 + lane) * 8];
    f16x8 br1 = *(const f16x8*)&wfrag_l[(size_t)(((0 * 4 + w) * 2 + 1) * 64 + lane) * 8];
    f16x8 bo0 = *(const f16x8*)&wfrag_l[(size_t)(((1 * 4 + w) * 2 + 0) * 64 + lane) * 8];
    f16x8 bo1 = *(const f16x8*)&wfrag_l[(size_t)(((1 * 4 + w) * 2 + 1) * 64 + lane) * 8];
    int r = lane & 15, kq = lane >> 4;
    float bc = bias[w * 16 + r];
    float w4rv = 0.f, w4ov = 0.f;
    if (FINAL) { w4rv = Wrel4[w * 16 + r]; w4ov = Wroot4[w * 16 + r]; }

    // ---- gather phase (round-9 form, packed records: 4 edges per int4) ----
    int qw = t >> 4, l = t & 15;
    int hi8 = l >> 3, f8 = l & 7;
    #pragma unroll
    for (int rr = 0; rr < 2; ++rr) {
        int node = rowbase + qw + rr * 16;
        float a[8] = {0.f, 0.f, 0.f, 0.f, 0.f, 0.f, 0.f, 0.f};
        if (node < N_NODES) {
            int beg = offs[node], end = offs[node + 1];
            int i = beg;
            for (; i + 4 < end; i += 8) {
                int4 pk0 = *(const int4*)(epack + i);
                int4 pk1 = *(const int4*)(epack + i + 4);
                int e0 = hi8 ? pk0.z : pk0.x;
                int e1 = hi8 ? pk0.w : pk0.y;
                int e2 = hi8 ? pk1.z : pk1.x;
                int e3 = hi8 ? pk1.w : pk1.y;
                f16x8 r0 = *(const f16x8*)(hin + (size_t)(e0 & 0xFFFF) * 64 + f8 * 8);
                f16x8 r1 = *(const f16x8*)(hin + (size_t)(e1 & 0xFFFF) * 64 + f8 * 8);
                f16x8 r2 = *(const f16x8*)(hin + (size_t)(e2 & 0xFFFF) * 64 + f8 * 8);
                f16x8 r3 = *(const f16x8*)(hin + (size_t)(e3 & 0xFFFF) * 64 + f8 * 8);
                float w0 = upw(e0), w1 = upw(e1), w2 = upw(e2), w3 = upw(e3);
                #pragma unroll
                for (int j = 0; j < 8; ++j) {
                    a[j] = fmaf(w0, (float)r0[j], a[j]);
                    a[j] = fmaf(w1, (float)r1[j], a[j]);
                    a[j] = fmaf(w2, (float)r2[j], a[j]);
                    a[j] = fmaf(w3, (float)r3[j], a[j]);
                }
            }
            if (i < end) {   // exactly 4 remaining (rows padded to x4)
                int4 pk = *(const int4*)(epack + i);
                int e0 = hi8 ? pk.z : pk.x;
                int e1 = hi8 ? pk.w : pk.y;
                f16x8 r0 = *(const f16x8*)(hin + (size_t)(e0 & 0xFFFF) * 64 + f8 * 8);
                f16x8 r1 = *(const f16x8*)(hin + (size_t)(e1 & 0xFFFF) * 64 + f8 * 8);
                float w0 = upw(e0), w1 = upw(e1);
                #pragma unroll
                for (int j = 0; j < 8; ++j) {
                    a[j] = fmaf(w0, (float)r0[j], a[j]);
                    a[j] = fmaf(w1, (float)r1[j], a[j]);
                }
            }
        }
        #pragma unroll
        for (int j = 0; j < 8; ++j) a[j] += __shfl_xor(a[j], 8, 64);
        f16x8 wv;
        #pragma unroll
        for (int j = 0; j < 8; ++j) {
            _Float16 hh = (_Float16)a[j];
            wv[j] = hi8 ? (_Float16)(a[j] - (float)hh) : hh;
        }
        int row = qw + rr * 16;
        _Float16* dstp = hi8 ? &aggrLo[row][f8 * 8] : &aggrHi[row][f8 * 8];
        *(f16x8*)dstp = wv;
    }
    __syncthreads();

    // ---- MFMA phase: wave w owns column tile ct=w ----
    #pragma unroll
    for (int g = 0; g < 2; ++g) {
        int lr = g * 16 + r;
        int grow = min(rowbase + lr, N_NODES - 1);
        f32x4 acc = {bc, bc, bc, bc};
        {
            f16x8 Ah = *(const f16x8*)&aggrHi[lr][0 * 32 + kq * 8];
            f16x8 Al = *(const f16x8*)&aggrLo[lr][0 * 32 + kq * 8];
            f16x8 Ar = *(const f16x8*)&hin[(size_t)grow * 64 + 0 * 32 + kq * 8];
            acc = __builtin_amdgcn_mfma_f32_16x16x32_f16(Ah, br0, acc, 0, 0, 0);
            acc = __builtin_amdgcn_mfma_f32_16x16x32_f16(Al, br0, acc, 0, 0, 0);
            acc = __builtin_amdgcn_mfma_f32_16x16x32_f16(Ar, bo0, acc, 0, 0, 0);
        }
        {
            f16x8 Ah = *(const f16x8*)&aggrHi[lr][1 * 32 + kq * 8];
            f16x8 Al = *(const f16x8*)&aggrLo[lr][1 * 32 + kq * 8];
            f16x8 Ar = *(const f16x8*)&hin[(size_t)grow * 64 + 1 * 32 + kq * 8];
            acc = __builtin_amdgcn_mfma_f32_16x16x32_f16(Ah, br1, acc, 0, 0, 0);
            acc = __builtin_amdgcn_mfma_f32_16x16x32_f16(Al, br1, acc, 0, 0, 0);
            acc = __builtin_amdgcn_mfma_f32_16x16x32_f16(Ar, bo1, acc, 0, 0, 0);
        }
        if (FINAL) {
            #pragma unroll
            for (int j = 0; j < 4; ++j) {
                float o = fmaxf(acc[j], 0.f);
                float zz = o * w4rv, rv = o * w4ov;
                #pragma unroll
                for (int m = 1; m < 16; m <<= 1) {
                    zz += __shfl_xor(zz, m, 64);
                    rv += __shfl_xor(rv, m, 64);
                }
                if (r == 0) {
                    int lrow = g * 16 + (lane >> 4) * 4 + j;
                    zpart[w][lrow] = zz;
                    rpart[w][lrow] = rv;
                }
            }
        } else {
            #pragma unroll
            for (int j = 0; j < 4; ++j) {
                int row = rowbase + g * 16 + (lane >> 4) * 4 + j;
                if (row < N_NODES)
                    hout[(size_t)row * 64 + w * 16 + r] = (_Float16)fmaxf(acc[j], 0.f);
            }
        }
    }
    if (FINAL) {
        __syncthreads();
        if (t < 32) {
            int row = rowbase + t;
            if (row < N_NODES) {
                z[row] = zpart[0][t] + zpart[1][t] + zpart[2][t] + zpart[3][t];
                root[row] = rpart[0][t] + rpart[1][t] + rpart[2][t] + rpart[3][t];
            }
        }
    }
}

// ---------------- final scalar aggregation + sigmoid (4 lanes per node) ----------------

__launch_bounds__(256)
__global__ void final_aggr(const int* __restrict__ offs, const int* __restrict__ epack,
                           const float* __restrict__ z, const float* __restrict__ root,
                           const float* __restrict__ b4, float* __restrict__ out) {
    int tid = blockIdx.x * blockDim.x + threadIdx.x;
    int node = tid >> 2, g = tid & 3;
    if (node >= N_NODES) return;
    int beg = offs[node], end = offs[node + 1];
    float a = 0.f;
    int i = beg + g;
    for (; i + 4 < end; i += 8) {
        int e0 = epack[i], e1 = epack[i + 4];
        a = fmaf(upw(e0), z[e0 & 0xFFFF], a);
        a = fmaf(upw(e1), z[e1 & 0xFFFF], a);
    }
    if (i < end) {
        int e = epack[i];
        a = fmaf(upw(e), z[e & 0xFFFF], a);
    }
    a += __shfl_xor(a, 1, 64);
    a += __shfl_xor(a, 2, 64);
    if (g == 0) {
        float v = a + b4[0] + root[node];
        out[node] = 1.f / (1.f + expf(-v));
    }
}

// ---------------- launch ----------------

extern "C" void kernel_launch(void* const* d_in, const int* in_sizes, int n_in,
                              void* d_out, int out_size, void* d_ws, size_t ws_size,
                              hipStream_t stream) {
    const float* x = (const float*)d_in[0];
    const int* eidx = (const int*)d_in[1];
    const float* ew = (const float*)d_in[2];
    const float* Wrel[5];
    const float* brel[5];
    const float* Wroot[5];
    for (int i = 0; i < 5; ++i) {
        Wrel[i] = (const float*)d_in[3 + 3 * i];
        brel[i] = (const float*)d_in[4 + 3 * i];
        Wroot[i] = (const float*)d_in[5 + 3 * i];
    }
    const int* src = eidx;
    const int* dst = eidx + N_EDGES;
    float* out = (float*)d_out;

    char* ws = (char*)d_ws;
    size_t off = 0;
    auto alloc = [&](size_t bytes) -> void* {
        void* p = ws + off;
        off = (off + bytes + 255) & ~(size_t)255;
        return p;
    };
    int* h = (int*)alloc((size_t)(SCAN_N + 256) * 4);
    int* blocksums = (int*)alloc(512 * 4);
    int* counts = (int*)alloc((size_t)N_NODES * 4);
    int* offs = (int*)alloc((size_t)(N_NODES + 1) * 4);
    int* epack = (int*)alloc((size_t)MAXEPAD * 4);
    _Float16* h0 = (_Float16*)alloc((size_t)N_NODES * 64 * 2);
    _Float16* h1 = (_Float16*)alloc((size_t)N_NODES * 64 * 2);
    _Float16* wfrag = (_Float16*)alloc((size_t)3 * 8192 * 2);
    _Float16* xh = (_Float16*)alloc((size_t)XELEMS * 2);
    float* z = (float*)alloc((size_t)N_NODES * 4);
    float* root = (float*)alloc((size_t)N_NODES * 4);
    int2* ecoarse = (int2*)h0;  // disjoint lifetime: sort phase only (6.4 MB == h0 size)
    (void)ws_size; (void)in_sizes; (void)n_in; (void)out_size;

    // ---- CSR build: counting sort, rows padded to x4 (+fused wconv + x->fp16) ----
    hipMemsetAsync(counts, 0, (size_t)N_NODES * 4, stream);
    hist_kernel<<<NCHUNK + 3 + XCONV_B, 256, 0, stream>>>(dst, h, counts,
                                                Wrel[1], Wroot[1], Wrel[2], Wroot[2],
                                                Wrel[3], Wroot[3], wfrag, x, xh);
    scan_sums<<<NSB, 256, 0, stream>>>(h, counts, blocksums);
    scan_apply<<<NSB, 256, 0, stream>>>(h, offs, counts, blocksums);
    scatter_coarse<<<NCHUNK, 256, 0, stream>>>(src, dst, ew, h, ecoarse);
    fine_sort<<<NBUCKET, 256, 0, stream>>>(h, offs, ecoarse, epack);

    const int NODE_BLOCKS = N_NODES * 64 / 256;  // 12500
    const int FB = (N_NODES + 31) / 32;          // 1563

    // ---- layer 0 (fused gather13 + VALU GEMM, fp16 x) -> h0 fp16 ----
    layer0_fused<<<NODE_BLOCKS, 256, 0, stream>>>(offs, epack, xh, Wrel[0], brel[0], Wroot[0], h0);

    // ---- layers 1..3 fused gather + MFMA ----
    layer_fused<false><<<FB, 256, 0, stream>>>(offs, epack, h0, wfrag, brel[1], h1,
                                               nullptr, nullptr, nullptr, nullptr);
    layer_fused<false><<<FB, 256, 0, stream>>>(offs, epack, h1, wfrag + 8192, brel[2], h0,
                                               nullptr, nullptr, nullptr, nullptr);
    layer_fused<true><<<FB, 256, 0, stream>>>(offs, epack, h0, wfrag + 16384, brel[3], nullptr,
                                              Wrel[4], Wroot[4], z, root);

    // ---- layer 4 scalar aggregation + sigmoid ----
    final_aggr<<<(N_NODES * 4 + 255) / 256, 256, 0, stream>>>(offs, epack, z, root, brel[4], out);
}